// Round 2
// baseline (25825.983 us; speedup 1.0000x reference)
//
#include <hip/hip_runtime.h>

// LTC scan, one WG per batch item (64 WGs). 1024 threads = 16 waves.
// Thread (jj = tid&127, p = tid>>7) owns W_rec rows jj and jj+128 over the
// 32-wide k-slice [32p, 32p+32) -> 64 f32 VGPRs, plus W_in slices (32 VGPRs).
// r=2 reuse: one h-slice read feeds two output rows, halving LDS broadcast
// traffic. p is wave-uniform -> all h/x LDS reads are broadcasts.
// Partials reduced via stride-257 LDS array (conflict-free), finalized by
// tid<256. Input-proj partial px computed once per t, folded into every
// layer's partial. p=7 threads stage x(t+1) during the finalize phase.

__device__ __forceinline__ float fast_tanh(float z) {
    float e = __expf(2.0f * z);        // inf-safe: e=inf -> 1, e=0 -> -1
    return 1.0f - 2.0f / (e + 1.0f);
}

__global__ void __launch_bounds__(1024, 4)
ltc_scan_kernel(const float* __restrict__ x,       // [B,T,I]
                const float* __restrict__ W_in,    // [H,I]
                const float* __restrict__ b_in,    // [H]
                const float* __restrict__ W_rec,   // [H,H]
                const float* __restrict__ b_rec,   // [H]
                const float* __restrict__ tau,     // [H]
                const int*   __restrict__ num_layers,
                float*       __restrict__ out,     // [B,H]
                int T)
{
    constexpr int H = 256, I = 128;
    const int b   = blockIdx.x;
    const int tid = threadIdx.x;
    const int jj  = tid & 127;        // output pair: rows jj, jj+128
    const int p   = tid >> 7;         // slice index 0..7 (wave-uniform)
    const int L   = num_layers[0];

    __shared__ float h_lds[H];
    __shared__ float xs[I];
    __shared__ float part[8 * 257];   // [p][j], stride 257 -> conflict-free

    // ---- weights to registers (96 f32 total per thread) ----
    float wA[32], wB[32];
    {
        const float* ra = &W_rec[jj * H + p * 32];
        const float* rb = &W_rec[(jj + 128) * H + p * 32];
        #pragma unroll 2
        for (int i = 0; i < 32; i += 4) {
            float4 va = *(const float4*)&ra[i];
            float4 vb = *(const float4*)&rb[i];
            wA[i]=va.x; wA[i+1]=va.y; wA[i+2]=va.z; wA[i+3]=va.w;
            wB[i]=vb.x; wB[i+1]=vb.y; wB[i+2]=vb.z; wB[i+3]=vb.w;
        }
    }
    float uA[16], uB[16];
    {
        const float* ra = &W_in[jj * I + p * 16];
        const float* rb = &W_in[(jj + 128) * I + p * 16];
        #pragma unroll 2
        for (int i = 0; i < 16; i += 4) {
            float4 va = *(const float4*)&ra[i];
            float4 vb = *(const float4*)&rb[i];
            uA[i]=va.x; uA[i+1]=va.y; uA[i+2]=va.z; uA[i+3]=va.w;
            uB[i]=vb.x; uB[i+1]=vb.y; uB[i+2]=vb.z; uB[i+3]=vb.w;
        }
    }

    // ---- finalizer state: thread j = tid (<256) owns h[j] ----
    float hj = 0.f, sj = 0.f, brj = 0.f, bij = 0.f;
    if (tid < H) {
        sj  = 0.1f / fminf(fmaxf(tau[tid], 0.1f), 5.0f);
        brj = b_rec[tid];
        bij = b_in[tid];
        h_lds[tid] = 0.0f;
    }
    const float* xb = x + (size_t)b * T * I;
    if (tid < I) xs[tid] = xb[tid];   // stage x(0)
    __syncthreads();

    const bool stager = (tid >= 896); // p==7 threads double as x stagers
    const int  k      = tid - 896;    // 0..127
    float xnext = 0.0f;

    for (int t = 0; t < T; ++t) {
        if (stager && t + 1 < T)
            xnext = xb[(size_t)(t + 1) * I + k];   // issue early, use late

        // input-projection partials, once per t (xs slice is broadcast)
        float pxA = 0.f, pxB = 0.f;
        {
            const float* xp = &xs[p * 16];
            #pragma unroll 2
            for (int i = 0; i < 16; i += 4) {
                float4 xv = *(const float4*)&xp[i];
                pxA += uA[i]*xv.x + uA[i+1]*xv.y + uA[i+2]*xv.z + uA[i+3]*xv.w;
                pxB += uB[i]*xv.x + uB[i+1]*xv.y + uB[i+2]*xv.z + uB[i+3]*xv.w;
            }
        }

        for (int l = 0; l < L; ++l) {
            // recurrent partials; h slice broadcast-read, reused for 2 rows
            float prA = pxA, prB = pxB;
            const float* hp = &h_lds[p * 32];
            #pragma unroll 2
            for (int i = 0; i < 32; i += 4) {
                float4 hv = *(const float4*)&hp[i];
                prA += wA[i]*hv.x + wA[i+1]*hv.y + wA[i+2]*hv.z + wA[i+3]*hv.w;
                prB += wB[i]*hv.x + wB[i+1]*hv.y + wB[i+2]*hv.z + wB[i+3]*hv.w;
            }
            part[p * 257 + jj]       = prA;
            part[p * 257 + jj + 128] = prB;
            __syncthreads();

            if (tid < H) {
                float z = part[tid]         + part[257   + tid]
                        + part[2*257 + tid] + part[3*257 + tid]
                        + part[4*257 + tid] + part[5*257 + tid]
                        + part[6*257 + tid] + part[7*257 + tid]
                        + brj + bij;
                float a = fast_tanh(z);
                hj += sj * (a - hj);
                h_lds[tid] = hj;
            } else if (stager && l == L - 1 && t + 1 < T) {
                xs[k] = xnext;            // consumed after next barrier
            }
            __syncthreads();
        }
    }

    if (tid < H) out[(size_t)b * H + tid] = hj;
}

extern "C" void kernel_launch(void* const* d_in, const int* in_sizes, int n_in,
                              void* d_out, int out_size, void* d_ws, size_t ws_size,
                              hipStream_t stream) {
    const float* x     = (const float*)d_in[0];
    const float* W_in  = (const float*)d_in[1];
    const float* b_in  = (const float*)d_in[2];
    const float* W_rec = (const float*)d_in[3];
    const float* b_rec = (const float*)d_in[4];
    const float* tau   = (const float*)d_in[5];
    const int*   numl  = (const int*)d_in[6];

    const int H = in_sizes[2];            // 256
    const int I = in_sizes[1] / H;        // 128
    const int B = out_size / H;           // 64
    const int T = in_sizes[0] / (B * I);  // 4096

    ltc_scan_kernel<<<B, 1024, 0, stream>>>(x, W_in, b_in, W_rec, b_rec, tau,
                                            numl, (float*)d_out, T);
}

// Round 3
// 7581.317 us; speedup vs baseline: 3.4065x; 3.4065x over previous
//
#include <hip/hip_runtime.h>

// LTC scan, one WG per batch item (64 WGs, 1 CU each), 512 threads = 8 waves.
// Thread layout: lane=tid&63, wv=tid>>6; c=lane&3, qq=lane>>2.
//   k-slice  p = 4*(wv&3) + c       (16 slices of width 16)
//   row base q = 16*(wv>>2) + qq    (rows j = q + 32m, m=0..7)
// Each thread: wrec[8][16] + win[8][8] in registers (CONSTANT indices only —
// R2 lesson: partial unroll => dynamic index => scratch spill).
// One h-read (b128, 4 distinct addrs/wave, 16-fold broadcast) feeds 32 FMAs.
// Partials: quad_perm DPP butterfly reduces 4 slices in-register; quad lanes
// write disjoint m-subsets (2 ds_write_b32/wave); stride-5 rows + (g+m)&3
// rotation => conflict-free (finalize sums all 4, order irrelevant).
// Finalize: tid<256, 4 b32 reads + tanh + h write. Input proj once per t.

template <int CTRL>
__device__ __forceinline__ float qperm(float v) {
    return __int_as_float(
        __builtin_amdgcn_update_dpp(0, __float_as_int(v), CTRL, 0xF, 0xF, true));
}

__device__ __forceinline__ float fast_tanh(float z) {
    float e = __expf(2.0f * z);        // inf-safe
    return 1.0f - 2.0f / (e + 1.0f);
}

__global__ void __launch_bounds__(512, 2)
ltc_scan_kernel(const float* __restrict__ x,       // [B,T,I]
                const float* __restrict__ W_in,    // [H,I]
                const float* __restrict__ b_in,    // [H]
                const float* __restrict__ W_rec,   // [H,H]
                const float* __restrict__ b_rec,   // [H]
                const float* __restrict__ tau,     // [H]
                const int*   __restrict__ num_layers,
                float*       __restrict__ out,     // [B,H]
                int T)
{
    constexpr int H = 256, I = 128;
    const int b    = blockIdx.x;
    const int tid  = threadIdx.x;
    const int lane = tid & 63;
    const int wv   = tid >> 6;
    const int c    = lane & 3;
    const int qq   = lane >> 2;
    const int p    = 4 * (wv & 3) + c;     // k-slice [16p,16p+16)
    const int q    = 16 * (wv >> 2) + qq;  // rows q+32m
    const int g    = wv & 3;               // partial group
    const int L    = num_layers[0];

    __shared__ float h_lds[H];
    __shared__ float xs[I];
    __shared__ float part[H * 5 + 4];

    // ---- weights to registers; ALL loops fully unrolled (constant idx) ----
    float wrec[128];
#pragma unroll
    for (int m = 0; m < 8; ++m) {
        const float* rp = &W_rec[(q + 32 * m) * H + 16 * p];
#pragma unroll
        for (int i = 0; i < 16; i += 4) {
            float4 v = *(const float4*)&rp[i];
            wrec[m * 16 + i]     = v.x;
            wrec[m * 16 + i + 1] = v.y;
            wrec[m * 16 + i + 2] = v.z;
            wrec[m * 16 + i + 3] = v.w;
        }
    }
    float win[64];
#pragma unroll
    for (int m = 0; m < 8; ++m) {
        const float* rp = &W_in[(q + 32 * m) * I + 8 * p];
#pragma unroll
        for (int i = 0; i < 8; i += 4) {
            float4 v = *(const float4*)&rp[i];
            win[m * 8 + i]     = v.x;
            win[m * 8 + i + 1] = v.y;
            win[m * 8 + i + 2] = v.z;
            win[m * 8 + i + 3] = v.w;
        }
    }

    // ---- finalize-thread state (tid<256 owns row tid) ----
    float hj = 0.f, sj = 0.f, brj = 0.f, bij = 0.f;
    if (tid < H) {
        sj  = 0.1f / fminf(fmaxf(tau[tid], 0.1f), 5.0f);
        brj = b_rec[tid];
        bij = b_in[tid];
        h_lds[tid] = 0.0f;
    }
    const float* xb = x + (size_t)b * T * I;
    if (tid < I) xs[tid] = xb[tid];        // x(0)
    __syncthreads();

    const bool stager = (tid >= 384);      // waves 6,7 load x(t+1)
    const int  xk     = tid - 384;         // 0..127
    float xnext = 0.0f;

    const float4* hp4 = (const float4*)&h_lds[16 * p];
    const float4* xp4 = (const float4*)&xs[8 * p];

    for (int t = 0; t < T; ++t) {
        if (stager && t + 1 < T)
            xnext = xb[(size_t)(t + 1) * I + xk];

        // ---- input projection partials, once per t ----
        float px[8];
#pragma unroll
        for (int m = 0; m < 8; ++m) px[m] = 0.f;
#pragma unroll
        for (int k = 0; k < 2; ++k) {
            float4 xv = xp4[k];
#pragma unroll
            for (int m = 0; m < 8; ++m) {
                px[m] += win[m * 8 + 4 * k]     * xv.x
                       + win[m * 8 + 4 * k + 1] * xv.y
                       + win[m * 8 + 4 * k + 2] * xv.z
                       + win[m * 8 + 4 * k + 3] * xv.w;
            }
        }

        for (int l = 0; l < L; ++l) {
            // ---- recurrent partials ----
            float acc[8];
#pragma unroll
            for (int m = 0; m < 8; ++m) acc[m] = px[m];
#pragma unroll
            for (int k = 0; k < 4; ++k) {
                float4 hv = hp4[k];
#pragma unroll
                for (int m = 0; m < 8; ++m) {
                    acc[m] += wrec[m * 16 + 4 * k]     * hv.x
                            + wrec[m * 16 + 4 * k + 1] * hv.y
                            + wrec[m * 16 + 4 * k + 2] * hv.z
                            + wrec[m * 16 + 4 * k + 3] * hv.w;
                }
            }

            // ---- quad butterfly: sum the 4 slices held in each quad ----
#pragma unroll
            for (int m = 0; m < 8; ++m) {
                acc[m] += qperm<0xB1>(acc[m]);   // xor 1
                acc[m] += qperm<0x4E>(acc[m]);   // xor 2
            }

            // ---- quad lanes write disjoint m: lane c writes m=c and m=c+4 ----
            {
                float v0 = (c == 0) ? acc[0] : (c == 1) ? acc[1]
                         : (c == 2) ? acc[2] : acc[3];
                float v1 = (c == 0) ? acc[4] : (c == 1) ? acc[5]
                         : (c == 2) ? acc[6] : acc[7];
                int j0 = q + 32 * c;
                int j1 = q + 32 * (c + 4);
                part[j0 * 5 + ((g + c) & 3)] = v0;
                part[j1 * 5 + ((g + c) & 3)] = v1;  // (g+c+4)&3 == (g+c)&3
            }
            __syncthreads();

            // ---- finalize ----
            if (tid < H) {
                const float* pp = &part[tid * 5];
                float z = (pp[0] + pp[1]) + (pp[2] + pp[3]) + brj + bij;
                float a = fast_tanh(z);
                hj += sj * (a - hj);
                h_lds[tid] = hj;
            } else if (stager && l == L - 1 && t + 1 < T) {
                xs[xk] = xnext;            // safe: px for this t already done
            }
            __syncthreads();
        }
    }

    if (tid < H) out[(size_t)b * H + tid] = hj;
}

extern "C" void kernel_launch(void* const* d_in, const int* in_sizes, int n_in,
                              void* d_out, int out_size, void* d_ws, size_t ws_size,
                              hipStream_t stream) {
    const float* x     = (const float*)d_in[0];
    const float* W_in  = (const float*)d_in[1];
    const float* b_in  = (const float*)d_in[2];
    const float* W_rec = (const float*)d_in[3];
    const float* b_rec = (const float*)d_in[4];
    const float* tau   = (const float*)d_in[5];
    const int*   numl  = (const int*)d_in[6];

    const int H = in_sizes[2];            // 256
    const int I = in_sizes[1] / H;        // 128
    const int B = out_size / H;           // 64
    const int T = in_sizes[0] / (B * I);  // 4096

    ltc_scan_kernel<<<B, 512, 0, stream>>>(x, W_in, b_in, W_rec, b_rec, tau,
                                           numl, (float*)d_out, T);
}

// Round 4
// 6517.731 us; speedup vs baseline: 3.9624x; 1.1632x over previous
//
#include <hip/hip_runtime.h>

// LTC scan, one WG per batch item (64 WGs), 512 thr = 8 waves.
// lane layout: p = lane&15 (k-slice of 16), sl = lane>>4, kf = lane&7.
// Thread computes 8 rows (32*wv + 8*sl + m) over cols [16p,16p+16):
// wrec = 128 VGPRs, constant-indexed, asm-pinned, amdgpu_waves_per_eu(2,2)
// to force the 256-VGPR tier (R3 lesson: compiler AGPR-offloads otherwise,
// paying v_accvgpr_read per use -> 2x VALU).
// Reduction over the 16 slices is fully in-wave: 4 DPP butterfly steps
// (quad xor1, quad xor2, row_half_mirror, row_mirror) -> every lane holds
// all 8 row sums; cndmask tree picks acc[kf]; finalize (tanh + h update)
// happens in the compute lanes. ONE barrier per layer (h double-buffered).
// h LDS stride-20 swizzle: b128 slice reads are 2-way-conflict (free).
// Input projection precomputed to d_ws by xproj_kernel (268 MB); fallback
// template path computes it in-kernel if ws_size is too small.

template <int CTRL>
__device__ __forceinline__ float qp(float v) {
    return __int_as_float(
        __builtin_amdgcn_update_dpp(0, __float_as_int(v), CTRL, 0xF, 0xF, true));
}

__device__ __forceinline__ float fast_tanh(float z) {
    float e = __expf(2.0f * z);        // inf-safe
    return 1.0f - 2.0f / (e + 1.0f);
}

// ---------------- input-projection pre-pass ----------------
// xp[row][c] = b_in[c] + sum_k x[row][k] * W_in[c][k];  row = b*T + t
// 1024 blocks x 256 thr; thread = one row; x row in 128 pinned VGPRs;
// W_in addresses are wave-uniform -> scalar loads; 109 us FMA floor.
__global__ void __launch_bounds__(256) __attribute__((amdgpu_waves_per_eu(2, 2)))
xproj_kernel(const float* __restrict__ x, const float* __restrict__ W_in,
             const float* __restrict__ b_in, float* __restrict__ xp)
{
    const int row = blockIdx.x * 256 + threadIdx.x;
    const float4* xrow = (const float4*)(x + (size_t)row * 128);
    float4 xr[32];
#pragma unroll
    for (int i = 0; i < 32; ++i) xr[i] = xrow[i];
#pragma unroll
    for (int i = 0; i < 32; ++i)
        asm volatile("" : "+v"(xr[i].x), "+v"(xr[i].y), "+v"(xr[i].z), "+v"(xr[i].w));

    float* o = xp + (size_t)row * 256;
#pragma unroll 1
    for (int c4 = 0; c4 < 64; ++c4) {
        const float* wr = W_in + (size_t)c4 * 4 * 128;
        float4 acc = *(const float4*)&b_in[4 * c4];
#pragma unroll
        for (int i = 0; i < 32; ++i) {
            float4 xv = xr[i];
            float4 w0 = *(const float4*)&wr[0 * 128 + 4 * i];
            float4 w1 = *(const float4*)&wr[1 * 128 + 4 * i];
            float4 w2 = *(const float4*)&wr[2 * 128 + 4 * i];
            float4 w3 = *(const float4*)&wr[3 * 128 + 4 * i];
            acc.x += w0.x*xv.x + w0.y*xv.y + w0.z*xv.z + w0.w*xv.w;
            acc.y += w1.x*xv.x + w1.y*xv.y + w1.z*xv.z + w1.w*xv.w;
            acc.z += w2.x*xv.x + w2.y*xv.y + w2.z*xv.z + w2.w*xv.w;
            acc.w += w3.x*xv.x + w3.y*xv.y + w3.z*xv.z + w3.w*xv.w;
        }
        ((float4*)o)[c4] = acc;
    }
}

// ---------------- recurrent scan ----------------
template <bool USE_XP>
__global__ void __launch_bounds__(512) __attribute__((amdgpu_waves_per_eu(2, 2)))
ltc_scan(const float* __restrict__ x,      // [B,T,I]   (fallback path)
         const float* __restrict__ xp,     // [B*T,H]   (primary path)
         const float* __restrict__ W_in,   // [H,I]
         const float* __restrict__ b_in,   // [H]
         const float* __restrict__ W_rec,  // [H,H]
         const float* __restrict__ b_rec,  // [H]
         const float* __restrict__ tau,    // [H]
         const int*   __restrict__ num_layers,
         float*       __restrict__ out,    // [B,H]
         int T)
{
    constexpr int H = 256, I = 128;
    const int b    = blockIdx.x;
    const int tid  = threadIdx.x;
    const int lane = tid & 63;
    const int wv   = tid >> 6;
    const int p    = lane & 15;            // k-slice [16p, 16p+16)
    const int sl   = lane >> 4;            // 0..3
    const int kf   = lane & 7;             // finalize sub-row
    const int rowbase = 32 * wv + 8 * sl;  // this group's 8 rows
    const int rowf    = rowbase + kf;      // this lane finalizes rowf
    const int L    = num_layers[0];

    __shared__ float hbuf[2][320];         // stride-20 swizzled h, dbuf
    __shared__ float xsb[2][192];          // stride-12 swizzled x (fallback)

    // ---- W_rec slice to registers, pinned ----
    float w[8][16];
#pragma unroll
    for (int m = 0; m < 8; ++m) {
        const float* rp = &W_rec[(rowbase + m) * H + 16 * p];
#pragma unroll
        for (int i = 0; i < 16; i += 4) {
            float4 v = *(const float4*)&rp[i];
            w[m][i] = v.x; w[m][i+1] = v.y; w[m][i+2] = v.z; w[m][i+3] = v.w;
        }
    }
#pragma unroll
    for (int m = 0; m < 8; ++m)
#pragma unroll
        for (int i = 0; i < 16; ++i) asm volatile("" : "+v"(w[m][i]));

    // fallback-only: W_in slice (8 wide) + b_in
    float wi[8][8];
    float bij = 0.f;
    if (!USE_XP) {
#pragma unroll
        for (int m = 0; m < 8; ++m) {
            const float* rp = &W_in[(rowbase + m) * I + 8 * p];
#pragma unroll
            for (int i = 0; i < 8; i += 4) {
                float4 v = *(const float4*)&rp[i];
                wi[m][i] = v.x; wi[m][i+1] = v.y; wi[m][i+2] = v.z; wi[m][i+3] = v.w;
            }
        }
#pragma unroll
        for (int m = 0; m < 8; ++m)
#pragma unroll
            for (int i = 0; i < 8; ++i) asm volatile("" : "+v"(wi[m][i]));
        bij = b_in[rowf];
    }

    // per-lane finalize constants
    const float sj  = 0.1f / fminf(fmaxf(tau[rowf], 0.1f), 5.0f);
    const float brj = b_rec[rowf];
    float hj = 0.0f;

    // zero h buffers
    for (int i = tid; i < 2 * 320; i += 512) ((float*)hbuf)[i] = 0.0f;

    const float* xb    = x + (size_t)b * T * I;
    const float* xprow = xp + (size_t)b * T * H;
    float xt_cur = 0.0f;
    if (USE_XP) xt_cur = xprow[rowf];
    if (!USE_XP && tid < 32) {             // stage x(0) swizzled
        float4 v = *(const float4*)&xb[4 * tid];
        *(float4*)&xsb[0][12 * (tid >> 1) + 4 * (tid & 1)] = v;
    }
    __syncthreads();

    const float* rb = hbuf[0];
    float*       wb = hbuf[1];

    for (int t = 0; t < T; ++t) {
        // prefetch next timestep's input term (hidden under layer compute)
        float xt_next = 0.0f;
        if (USE_XP) {
            int tn = (t + 1 < T) ? t + 1 : t;
            xt_next = xprow[(size_t)tn * H + rowf];
        } else if (tid < 32 && t + 1 < T) {
            float4 v = *(const float4*)&xb[(size_t)(t + 1) * I + 4 * tid];
            *(float4*)&xsb[(t + 1) & 1][12 * (tid >> 1) + 4 * (tid & 1)] = v;
        }

        // fallback: per-slice input-projection partials, once per t
        float px[8];
        if (!USE_XP) {
            const float4* xv4 = (const float4*)&xsb[t & 1][12 * p];
            float4 x0 = xv4[0], x1 = xv4[1];
#pragma unroll
            for (int m = 0; m < 8; ++m) {
                px[m] = wi[m][0]*x0.x + wi[m][1]*x0.y + wi[m][2]*x0.z + wi[m][3]*x0.w
                      + wi[m][4]*x1.x + wi[m][5]*x1.y + wi[m][6]*x1.z + wi[m][7]*x1.w;
            }
        }

        for (int l = 0; l < L; ++l) {
            float acc[8];
#pragma unroll
            for (int m = 0; m < 8; ++m) acc[m] = USE_XP ? 0.0f : px[m];

            const float4* hv4 = (const float4*)&rb[20 * p];
#pragma unroll
            for (int k = 0; k < 4; ++k) {
                float4 hv = hv4[k];
#pragma unroll
                for (int m = 0; m < 8; ++m) {
                    acc[m] += w[m][4*k]   * hv.x + w[m][4*k+1] * hv.y
                            + w[m][4*k+2] * hv.z + w[m][4*k+3] * hv.w;
                }
            }

            // in-wave butterfly over the 16 slices
#pragma unroll
            for (int m = 0; m < 8; ++m) {
                acc[m] += qp<0xB1>(acc[m]);    // quad xor1
                acc[m] += qp<0x4E>(acc[m]);    // quad xor2
                acc[m] += qp<0x141>(acc[m]);   // row_half_mirror (8-group)
                acc[m] += qp<0x140>(acc[m]);   // row_mirror (16-group)
            }

            // select acc[kf] via cndmask tree
            float v01 = (kf & 1) ? acc[1] : acc[0];
            float v23 = (kf & 1) ? acc[3] : acc[2];
            float v45 = (kf & 1) ? acc[5] : acc[4];
            float v67 = (kf & 1) ? acc[7] : acc[6];
            float v03 = (kf & 2) ? v23 : v01;
            float v47 = (kf & 2) ? v67 : v45;
            float vv  = (kf & 4) ? v47 : v03;

            float z = vv + brj + (USE_XP ? xt_cur : bij);
            float a = fast_tanh(z);
            hj += sj * (a - hj);
            wb[20 * (rowf >> 4) + (rowf & 15)] = hj;  // dup lanes: same val/addr
            __syncthreads();

            float* tmp = (float*)rb; rb = wb; wb = tmp;
        }
        xt_cur = xt_next;
    }

    if ((lane & 15) < 8) out[(size_t)b * H + rowf] = hj;
}

extern "C" void kernel_launch(void* const* d_in, const int* in_sizes, int n_in,
                              void* d_out, int out_size, void* d_ws, size_t ws_size,
                              hipStream_t stream) {
    const float* x     = (const float*)d_in[0];
    const float* W_in  = (const float*)d_in[1];
    const float* b_in  = (const float*)d_in[2];
    const float* W_rec = (const float*)d_in[3];
    const float* b_rec = (const float*)d_in[4];
    const float* tau   = (const float*)d_in[5];
    const int*   numl  = (const int*)d_in[6];

    const int H  = in_sizes[2];            // 256
    const int I  = in_sizes[1] / H;        // 128
    const int B  = out_size / H;           // 64
    const int T  = in_sizes[0] / (B * I);  // 4096
    const size_t xp_bytes = (size_t)B * T * H * sizeof(float);

    if (ws_size >= xp_bytes) {
        float* xp = (float*)d_ws;
        xproj_kernel<<<(B * T) / 256, 256, 0, stream>>>(x, W_in, b_in, xp);
        ltc_scan<true><<<B, 512, 0, stream>>>(x, xp, W_in, b_in, W_rec, b_rec,
                                              tau, numl, (float*)d_out, T);
    } else {
        ltc_scan<false><<<B, 512, 0, stream>>>(x, (const float*)d_ws, W_in, b_in,
                                               W_rec, b_rec, tau, numl,
                                               (float*)d_out, T);
    }
}